// Round 1
// baseline (501.015 us; speedup 1.0000x reference)
//
#include <hip/hip_runtime.h>
#include <hip/hip_bf16.h>

#define DIN 96
#define DOUT 32
#define NH 4
#define DTOT 128          // NH * DOUT, concat output width
#define SLOPE 0.2f
#define NPB 16            // nodes per block in feat_kernel
#define BSH 7             // bucket shift: 128 src nodes per bucket
#define BNODES 128
#define MAXB 1024         // max buckets (N <= 131072)
#define EPB 16384         // edges per block in bin kernels

// pack two fp32 -> two bf16 (RNE) in one uint
__device__ __forceinline__ unsigned int packbf2(float lo, float hi) {
    unsigned int a = __float_as_uint(lo), b = __float_as_uint(hi);
    a += 0x7fffu + ((a >> 16) & 1u);
    b += 0x7fffu + ((b >> 16) & 1u);
    return (a >> 16) | (b & 0xffff0000u);
}

// ---------------------------------------------------------------------------
// Kernel A: h[n] = x[n] @ W (all heads) stored as packed bf16, plus per-node
// attention exp factors:
//   usrc[n*4+head] = (exp(-as), exp(-0.2*as)),  as = h[n,head]·a[head,:32]
//   vdst[n*4+head] = (exp(-ad), exp(-0.2*ad))
// Edge coefficient ee = exp(-leaky(as+ad)) = min(u.x*v.x, u.y*v.y).
// ---------------------------------------------------------------------------
__global__ __launch_bounds__(256) void feat_kernel(
    const float* __restrict__ x, const float* __restrict__ W,
    const float* __restrict__ a,
    unsigned int* __restrict__ hq,      // [N*64] packed bf16 pairs
    float2* __restrict__ usrc, float2* __restrict__ vdst,
    int n_nodes)
{
    __shared__ float Wl[DIN * DTOT];
    __shared__ float xs[NPB * DIN];
    __shared__ float al[NH * 2 * DOUT];
    const int t = threadIdx.x;

    for (int i = t; i < DIN * DTOT; i += 256) {
        int k = i >> 7, c = i & 127;
        int head = c >> 5, j = c & 31;
        Wl[i] = W[head * (DIN * DOUT) + k * DOUT + j];
    }
    for (int i = t; i < NH * 2 * DOUT; i += 256) al[i] = a[i];

    const int node0 = blockIdx.x * NPB;
    for (int i = t; i < NPB * DIN; i += 256) {
        int gidx = node0 * DIN + i;
        xs[i] = (gidx < n_nodes * DIN) ? x[gidx] : 0.f;
    }
    __syncthreads();

    const int node = t >> 4;
    const int cb = (t & 15) << 3;
    float acc[8];
#pragma unroll
    for (int j = 0; j < 8; ++j) acc[j] = 0.f;

#pragma unroll 4
    for (int k = 0; k < DIN; ++k) {
        float xv = xs[node * DIN + k];
#pragma unroll
        for (int j = 0; j < 8; ++j)
            acc[j] += xv * Wl[k * DTOT + cb + j];
    }

    const int g = node0 + node;
    if (g < n_nodes) {
        uint4 pk;
        pk.x = packbf2(acc[0], acc[1]);
        pk.y = packbf2(acc[2], acc[3]);
        pk.z = packbf2(acc[4], acc[5]);
        pk.w = packbf2(acc[6], acc[7]);
        *(uint4*)&hq[(size_t)g * 64 + (cb >> 1)] = pk;
    }

    const int head = cb >> 5;
    const int j0 = cb & 31;
    float ps = 0.f, pd = 0.f;
#pragma unroll
    for (int j = 0; j < 8; ++j) {
        ps += acc[j] * al[head * 64 + j0 + j];
        pd += acc[j] * al[head * 64 + 32 + j0 + j];
    }
    ps += __shfl_xor(ps, 1); ps += __shfl_xor(ps, 2);
    pd += __shfl_xor(pd, 1); pd += __shfl_xor(pd, 2);
    if ((t & 3) == 0 && g < n_nodes) {
        usrc[g * NH + head] = make_float2(__expf(-ps), __expf(-SLOPE * ps));
        vdst[g * NH + head] = make_float2(__expf(-pd), __expf(-SLOPE * pd));
    }
}

// ---------------------------------------------------------------------------
// Two-level counting sort of edges by src.
// Level 1: coarse buckets of 128 src nodes. Level 2: per-bucket LDS sort.
// ---------------------------------------------------------------------------

// count edges per coarse bucket (LDS hist, one global atomic per block-bucket)
__global__ __launch_bounds__(256) void bincount_kernel(
    const int* __restrict__ esrc, int* __restrict__ counts, int n_edges, int nb)
{
    __shared__ int bc[MAXB];
    const int t = threadIdx.x;
    for (int i = t; i < nb; i += 256) bc[i] = 0;
    __syncthreads();
    const int base = blockIdx.x * EPB;
    const int end = min(base + EPB, n_edges);
    for (int e = base + t; e < end; e += 256)
        atomicAdd(&bc[esrc[e] >> BSH], 1);
    __syncthreads();
    for (int i = t; i < nb; i += 256)
        if (bc[i] > 0) atomicAdd(&counts[i], bc[i]);
}

// scan buckets: bbase (binned layout), gcur (reservation cursor),
// sbase (4-aligned slots layout with +512 pad slack per bucket)
__global__ __launch_bounds__(1024) void bscan_kernel(
    const int* __restrict__ counts, int* __restrict__ bbase,
    int* __restrict__ gcur, int* __restrict__ sbase, int nb)
{
    __shared__ int tmp[1024];
    const int t = threadIdx.x;
    int v = (t < nb) ? counts[t] : 0;
    tmp[t] = v;
    __syncthreads();
    for (int off = 1; off < 1024; off <<= 1) {
        int xv = (t >= off) ? tmp[t - off] : 0;
        __syncthreads();
        tmp[t] += xv;
        __syncthreads();
    }
    if (t < nb) {
        int excl = tmp[t] - v;
        bbase[t] = excl;
        gcur[t] = excl;
        sbase[t] = ((excl + 3) & ~3) + t * (4 * BNODES);
    }
}

// scatter edges (packed srcl|dst) into coarse bucket regions
__global__ __launch_bounds__(256) void binscatter_kernel(
    const int* __restrict__ esrc, const int* __restrict__ edst,
    int* __restrict__ gcur, unsigned int* __restrict__ binned,
    int n_edges, int nb)
{
    __shared__ int bc[MAXB];
    const int t = threadIdx.x;
    for (int i = t; i < nb; i += 256) bc[i] = 0;
    __syncthreads();
    const int base = blockIdx.x * EPB;
    const int end = min(base + EPB, n_edges);
    for (int e = base + t; e < end; e += 256)
        atomicAdd(&bc[esrc[e] >> BSH], 1);
    __syncthreads();
    // reserve a run per non-empty bucket; bc becomes the running cursor
    for (int i = t; i < nb; i += 256) {
        int c = bc[i];
        bc[i] = (c > 0) ? atomicAdd(&gcur[i], c) : 0;
    }
    __syncthreads();
    for (int e = base + t; e < end; e += 256) {
        int s = esrc[e];
        int pos = atomicAdd(&bc[s >> BSH], 1);
        binned[pos] = ((unsigned int)(s & (BNODES - 1)) << 17) | (unsigned int)edst[e];
    }
}

// per-bucket fine sort: LDS per-node hist + scan, write offs/deg and slots
__global__ __launch_bounds__(256) void binfine_kernel(
    const unsigned int* __restrict__ binned,
    const int* __restrict__ counts, const int* __restrict__ bbase,
    const int* __restrict__ sbase,
    int* __restrict__ offs, int* __restrict__ deg,
    int* __restrict__ slots, int n_nodes)
{
    __shared__ int dcnt[BNODES];
    __shared__ int sc[BNODES];
    __shared__ int dcur[BNODES];
    const int t = threadIdx.x;
    const int b = blockIdx.x;
    const int cnt = counts[b];
    const int start = bbase[b];
    const int sb = sbase[b];
    const int node0 = b << BSH;

    if (t < BNODES) dcnt[t] = 0;
    __syncthreads();
    for (int i = t; i < cnt; i += 256)
        atomicAdd(&dcnt[binned[start + i] >> 17], 1);
    __syncthreads();
    int pd = 0;
    if (t < BNODES) { pd = (dcnt[t] + 3) & ~3; sc[t] = pd; }
    __syncthreads();
    for (int off = 1; off < BNODES; off <<= 1) {
        int v = 0;
        if (t < BNODES && t >= off) v = sc[t - off];
        __syncthreads();
        if (t < BNODES) sc[t] += v;
        __syncthreads();
    }
    if (t < BNODES) {
        int o = sb + sc[t] - pd;   // 4-aligned per-node start
        dcur[t] = o;
        int node = node0 + t;
        if (node < n_nodes) { offs[node] = o; deg[node] = dcnt[t]; }
    }
    __syncthreads();
    for (int i = t; i < cnt; i += 256) {
        unsigned int w = binned[start + i];
        int pos = atomicAdd(&dcur[w >> 17], 1);
        slots[pos] = (int)(w & 0x1ffffu);
    }
}

// ---------------------------------------------------------------------------
// Gather: 64 lanes per node, 2 cols per lane (bf16x2 h loads).
// v2: 32-bit byte-offset addressing (one v_lshl_add_u32 per load, saddr form)
//     + 2-stage software pipeline: value loads for group k+4 are issued
//     before consuming group k (T14 issue-early/consume-late). Alternating
//     A/B register sets, manually unrolled -> no rotation movs.
// Accumulation order is bit-identical to v1 (edge j of each 4-group -> acc j).
// ---------------------------------------------------------------------------
__global__ __launch_bounds__(256) void gather_kernel(
    const int* __restrict__ slots, const int* __restrict__ offsets,
    const int* __restrict__ deg,
    const unsigned int* __restrict__ hv,    // [N*64] packed bf16 pairs
    const float2* __restrict__ usrc, const float2* __restrict__ vdst,
    float* __restrict__ out, int n_nodes)
{
    const int t = threadIdx.x;
    const int node = blockIdx.x * 4 + (t >> 6);
    if (node >= n_nodes) return;
    const int l = t & 63;          // cols {2l, 2l+1}
    const int head = l >> 4;
    const unsigned loff = (unsigned)l << 2;     // byte offset within hv row (256B)
    const unsigned hoff = (unsigned)head << 3;  // byte offset within vdst row (32B)
    const char* __restrict__ hvb = (const char*)hv;
    const char* __restrict__ vdb = (const char*)vdst;
    const float2 u = usrc[(unsigned)node * 4u + head];
    const int beg = offsets[node]; // multiple of 4
    const int d = deg[node];

    float ax0 = 0.f, ay0 = 0.f, ax1 = 0.f, ay1 = 0.f;
    float ax2 = 0.f, ay2 = 0.f, ax3 = 0.f, ay3 = 0.f;

#define LDV(c) (*(const float2*)(vdb + ((((unsigned)(c)) << 5) + hoff)))
#define LDW(c) (*(const unsigned int*)(hvb + ((((unsigned)(c)) << 8) + loff)))
#define COMP(vv, ww, AX, AY) do {                                   \
        float e_ = fminf(u.x * (vv).x, u.y * (vv).y);               \
        AX = fmaf(e_, __uint_as_float((ww) << 16), AX);             \
        AY = fmaf(e_, __uint_as_float((ww) & 0xffff0000u), AY);     \
    } while (0)

    int k = 0;
    if (d >= 4) {
        // prologue: group 0 into A
        int4 cA = *(const int4*)(slots + beg);
        float2 vA0 = LDV(cA.x), vA1 = LDV(cA.y), vA2 = LDV(cA.z), vA3 = LDV(cA.w);
        unsigned wA0 = LDW(cA.x), wA1 = LDW(cA.y), wA2 = LDW(cA.z), wA3 = LDW(cA.w);

        // steady state: A holds group k (loaded). Load B=k+4, compute A,
        // load A=k+8, compute B.
        for (; k + 12 <= d; k += 8) {
            int4 cB = *(const int4*)(slots + beg + k + 4);
            float2 vB0 = LDV(cB.x), vB1 = LDV(cB.y), vB2 = LDV(cB.z), vB3 = LDV(cB.w);
            unsigned wB0 = LDW(cB.x), wB1 = LDW(cB.y), wB2 = LDW(cB.z), wB3 = LDW(cB.w);
            COMP(vA0, wA0, ax0, ay0); COMP(vA1, wA1, ax1, ay1);
            COMP(vA2, wA2, ax2, ay2); COMP(vA3, wA3, ax3, ay3);
            int4 cN = *(const int4*)(slots + beg + k + 8);
            vA0 = LDV(cN.x); vA1 = LDV(cN.y); vA2 = LDV(cN.z); vA3 = LDV(cN.w);
            wA0 = LDW(cN.x); wA1 = LDW(cN.y); wA2 = LDW(cN.z); wA3 = LDW(cN.w);
            COMP(vB0, wB0, ax0, ay0); COMP(vB1, wB1, ax1, ay1);
            COMP(vB2, wB2, ax2, ay2); COMP(vB3, wB3, ax3, ay3);
        }
        // drain: A holds group k (valid). Maybe one more full group after it.
        if (k + 8 <= d) {
            int4 cB = *(const int4*)(slots + beg + k + 4);
            float2 vB0 = LDV(cB.x), vB1 = LDV(cB.y), vB2 = LDV(cB.z), vB3 = LDV(cB.w);
            unsigned wB0 = LDW(cB.x), wB1 = LDW(cB.y), wB2 = LDW(cB.z), wB3 = LDW(cB.w);
            COMP(vA0, wA0, ax0, ay0); COMP(vA1, wA1, ax1, ay1);
            COMP(vA2, wA2, ax2, ay2); COMP(vA3, wA3, ax3, ay3);
            COMP(vB0, wB0, ax0, ay0); COMP(vB1, wB1, ax1, ay1);
            COMP(vB2, wB2, ax2, ay2); COMP(vB3, wB3, ax3, ay3);
            k += 8;
        } else {
            COMP(vA0, wA0, ax0, ay0); COMP(vA1, wA1, ax1, ay1);
            COMP(vA2, wA2, ax2, ay2); COMP(vA3, wA3, ax3, ay3);
            k += 4;
        }
    }
    // scalar tail (<4 edges)
    for (; k < d; ++k) {
        int c = slots[beg + k];
        float2 v = LDV(c);
        unsigned w = LDW(c);
        COMP(v, w, ax0, ay0);
    }
#undef LDV
#undef LDW
#undef COMP

    float rx = (ax0 + ax1) + (ax2 + ax3);
    float ry = (ay0 + ay1) + (ay2 + ay3);
    rx = rx > 0.f ? rx : __expf(rx) - 1.f;
    ry = ry > 0.f ? ry : __expf(ry) - 1.f;
    ((float2*)out)[(unsigned)node * 64u + l] = make_float2(rx, ry);
}

extern "C" void kernel_launch(void* const* d_in, const int* in_sizes, int n_in,
                              void* d_out, int out_size, void* d_ws, size_t ws_size,
                              hipStream_t stream)
{
    const float* x  = (const float*)d_in[0];
    const float* W  = (const float*)d_in[1];
    const float* a  = (const float*)d_in[2];
    const int* esrc = (const int*)d_in[3];
    const int* edst = (const int*)d_in[4];
    const int n_nodes = in_sizes[0] / DIN;
    const int n_edges = in_sizes[3];
    float* out = (float*)d_out;

    const int nb = (n_nodes + BNODES - 1) >> BSH;

    // workspace layout
    unsigned int* hq = (unsigned int*)d_ws;                 // [N*64] bf16 pairs, 25.6MB
    float2* usrc = (float2*)(hq + (size_t)n_nodes * 64);    // [N*4]
    float2* vdst = usrc + (size_t)n_nodes * NH;             // [N*4]
    int* offs   = (int*)(vdst + (size_t)n_nodes * NH);      // [N]
    int* deg    = offs + n_nodes;                           // [N]
    int* counts = deg + n_nodes;                            // [MAXB]
    int* bbase  = counts + MAXB;                            // [MAXB]
    int* gcur   = bbase + MAXB;                             // [MAXB]
    int* sbase  = gcur + MAXB;                              // [MAXB]
    unsigned int* binned = (unsigned int*)(sbase + MAXB);   // [E]
    int* slots  = (int*)(binned + n_edges);                 // [E + 512*nb + 64]

    hipMemsetAsync(counts, 0, MAXB * sizeof(int), stream);

    feat_kernel<<<(n_nodes + NPB - 1) / NPB, 256, 0, stream>>>(
        x, W, a, hq, usrc, vdst, n_nodes);

    const int binblocks = (n_edges + EPB - 1) / EPB;
    bincount_kernel<<<binblocks, 256, 0, stream>>>(esrc, counts, n_edges, nb);
    bscan_kernel<<<1, 1024, 0, stream>>>(counts, bbase, gcur, sbase, nb);
    binscatter_kernel<<<binblocks, 256, 0, stream>>>(
        esrc, edst, gcur, binned, n_edges, nb);
    binfine_kernel<<<nb, 256, 0, stream>>>(
        binned, counts, bbase, sbase, offs, deg, slots, n_nodes);

    gather_kernel<<<(n_nodes + 3) / 4, 256, 0, stream>>>(
        slots, offs, deg, hq, usrc, vdst, out, n_nodes);
}

// Round 2
// 495.374 us; speedup vs baseline: 1.0114x; 1.0114x over previous
//
#include <hip/hip_runtime.h>
#include <hip/hip_bf16.h>

#define DIN 96
#define DOUT 32
#define NH 4
#define DTOT 128          // NH * DOUT, concat output width
#define SLOPE 0.2f
#define NPBF 64           // nodes per block in feat_kernel (4 per thread)
#define BSH 7             // bucket shift: 128 src nodes per bucket
#define BNODES 128
#define MAXB 1024         // max buckets (N <= 131072)
#define EPB 16384         // edges per block in bin kernels

// pack two fp32 -> two bf16 (RNE) in one uint
__device__ __forceinline__ unsigned int packbf2(float lo, float hi) {
    unsigned int a = __float_as_uint(lo), b = __float_as_uint(hi);
    a += 0x7fffu + ((a >> 16) & 1u);
    b += 0x7fffu + ((b >> 16) & 1u);
    return (a >> 16) | (b & 0xffff0000u);
}

// ---------------------------------------------------------------------------
// Kernel A (v3): h[n] = x[n] @ W (all heads) -> packed bf16, plus per-node
// attention exp factors. Restructured for LDS throughput:
//   - 4 nodes/thread (64 nodes/block): 32 FMA per W-fragment read (was 8)
//   - W split into Wlo/Whi planes -> ds_read_b128 at 16B stride, bank-clean
//   - x read via guarded float4 global loads (L1-resident, wave-broadcast)
//   - LDS 49KB -> 3 blocks/CU (12 waves/CU, was 8)
//   - counts[] zeroing folded in (replaces hipMemsetAsync dispatch)
// Math is bit-identical to v2: same fma order (k ascending), same shfl tree.
// ---------------------------------------------------------------------------
__global__ __launch_bounds__(256) void feat_kernel(
    const float* __restrict__ x, const float* __restrict__ W,
    const float* __restrict__ a,
    unsigned int* __restrict__ hq,      // [N*64] packed bf16 pairs
    float2* __restrict__ usrc, float2* __restrict__ vdst,
    int* __restrict__ counts, int n_nodes)
{
    __shared__ float Wlo[DIN * 64];     // [k][cbi*4 + jj], cols 8*cbi + jj
    __shared__ float Whi[DIN * 64];     // [k][cbi*4 + jj], cols 8*cbi + 4 + jj
    __shared__ float al[NH * 2 * DOUT];
    const int t = threadIdx.x;

    if (blockIdx.x == 0)
        for (int i = t; i < MAXB; i += 256) counts[i] = 0;

    // stage W: linear read (coalesced), split write into lo/hi planes
    for (int i = t; i < DIN * DTOT; i += 256) {
        int k = i >> 7, c = i & 127;        // c = output col 0..127
        int head = c >> 5, j = c & 31;
        float w = W[head * (DIN * DOUT) + k * DOUT + j];
        int cbi = c >> 3, jj = c & 7;
        if (jj < 4) Wlo[(k << 6) + (cbi << 2) + jj] = w;
        else        Whi[(k << 6) + (cbi << 2) + (jj - 4)] = w;
    }
    for (int i = t; i < NH * 2 * DOUT; i += 256) al[i] = a[i];
    __syncthreads();

    const int cbi = t & 15;             // column block: cols 8*cbi .. 8*cbi+7
    const int ng = t >> 4;              // node group (4 nodes)
    const int node0 = blockIdx.x * NPBF;
    const int g0 = node0 + ng * 4;

    bool ok[4];
    const float* xp[4];
#pragma unroll
    for (int i = 0; i < 4; ++i) {
        ok[i] = (g0 + i) < n_nodes;
        xp[i] = x + (size_t)(g0 + i) * DIN;
    }

    float acc[4][8];
#pragma unroll
    for (int i = 0; i < 4; ++i)
#pragma unroll
        for (int j = 0; j < 8; ++j) acc[i][j] = 0.f;

    for (int k = 0; k < DIN; k += 4) {
        float4 xv[4];
#pragma unroll
        for (int i = 0; i < 4; ++i)
            xv[i] = ok[i] ? *(const float4*)(xp[i] + k)
                          : make_float4(0.f, 0.f, 0.f, 0.f);
#pragma unroll
        for (int kk = 0; kk < 4; ++kk) {
            const float4 wlo = *(const float4*)&Wlo[((k + kk) << 6) + (cbi << 2)];
            const float4 whi = *(const float4*)&Whi[((k + kk) << 6) + (cbi << 2)];
#pragma unroll
            for (int i = 0; i < 4; ++i) {
                const float xvv = (kk == 0) ? xv[i].x : (kk == 1) ? xv[i].y
                                 : (kk == 2) ? xv[i].z : xv[i].w;
                acc[i][0] = fmaf(xvv, wlo.x, acc[i][0]);
                acc[i][1] = fmaf(xvv, wlo.y, acc[i][1]);
                acc[i][2] = fmaf(xvv, wlo.z, acc[i][2]);
                acc[i][3] = fmaf(xvv, wlo.w, acc[i][3]);
                acc[i][4] = fmaf(xvv, whi.x, acc[i][4]);
                acc[i][5] = fmaf(xvv, whi.y, acc[i][5]);
                acc[i][6] = fmaf(xvv, whi.z, acc[i][6]);
                acc[i][7] = fmaf(xvv, whi.w, acc[i][7]);
            }
        }
    }

    const int head = cbi >> 2;
    const int j0 = (cbi & 3) << 3;
#pragma unroll
    for (int i = 0; i < 4; ++i) {
        float ps = 0.f, pd = 0.f;
#pragma unroll
        for (int j = 0; j < 8; ++j) {
            ps += acc[i][j] * al[head * 64 + j0 + j];
            pd += acc[i][j] * al[head * 64 + 32 + j0 + j];
        }
        ps += __shfl_xor(ps, 1); ps += __shfl_xor(ps, 2);
        pd += __shfl_xor(pd, 1); pd += __shfl_xor(pd, 2);
        const int g = g0 + i;
        if (ok[i]) {
            uint4 pk;
            pk.x = packbf2(acc[i][0], acc[i][1]);
            pk.y = packbf2(acc[i][2], acc[i][3]);
            pk.z = packbf2(acc[i][4], acc[i][5]);
            pk.w = packbf2(acc[i][6], acc[i][7]);
            *(uint4*)&hq[(size_t)g * 64 + (cbi << 2)] = pk;
            if ((cbi & 3) == 0) {
                usrc[g * NH + head] = make_float2(__expf(-ps), __expf(-SLOPE * ps));
                vdst[g * NH + head] = make_float2(__expf(-pd), __expf(-SLOPE * pd));
            }
        }
    }
}

// ---------------------------------------------------------------------------
// Two-level counting sort of edges by src.
// Level 1: coarse buckets of 128 src nodes. Level 2: per-bucket LDS sort.
// ---------------------------------------------------------------------------

// count edges per coarse bucket (LDS hist, one global atomic per block-bucket)
__global__ __launch_bounds__(256) void bincount_kernel(
    const int* __restrict__ esrc, int* __restrict__ counts, int n_edges, int nb)
{
    __shared__ int bc[MAXB];
    const int t = threadIdx.x;
    for (int i = t; i < nb; i += 256) bc[i] = 0;
    __syncthreads();
    const int base = blockIdx.x * EPB;
    const int end = min(base + EPB, n_edges);
    for (int e = base + t; e < end; e += 256)
        atomicAdd(&bc[esrc[e] >> BSH], 1);
    __syncthreads();
    for (int i = t; i < nb; i += 256)
        if (bc[i] > 0) atomicAdd(&counts[i], bc[i]);
}

// scan buckets: bbase (binned layout), gcur (reservation cursor),
// sbase (4-aligned slots layout with +512 pad slack per bucket)
__global__ __launch_bounds__(1024) void bscan_kernel(
    const int* __restrict__ counts, int* __restrict__ bbase,
    int* __restrict__ gcur, int* __restrict__ sbase, int nb)
{
    __shared__ int tmp[1024];
    const int t = threadIdx.x;
    int v = (t < nb) ? counts[t] : 0;
    tmp[t] = v;
    __syncthreads();
    for (int off = 1; off < 1024; off <<= 1) {
        int xv = (t >= off) ? tmp[t - off] : 0;
        __syncthreads();
        tmp[t] += xv;
        __syncthreads();
    }
    if (t < nb) {
        int excl = tmp[t] - v;
        bbase[t] = excl;
        gcur[t] = excl;
        sbase[t] = ((excl + 3) & ~3) + t * (4 * BNODES);
    }
}

// scatter edges (packed srcl|dst) into coarse bucket regions
__global__ __launch_bounds__(256) void binscatter_kernel(
    const int* __restrict__ esrc, const int* __restrict__ edst,
    int* __restrict__ gcur, unsigned int* __restrict__ binned,
    int n_edges, int nb)
{
    __shared__ int bc[MAXB];
    const int t = threadIdx.x;
    for (int i = t; i < nb; i += 256) bc[i] = 0;
    __syncthreads();
    const int base = blockIdx.x * EPB;
    const int end = min(base + EPB, n_edges);
    for (int e = base + t; e < end; e += 256)
        atomicAdd(&bc[esrc[e] >> BSH], 1);
    __syncthreads();
    // reserve a run per non-empty bucket; bc becomes the running cursor
    for (int i = t; i < nb; i += 256) {
        int c = bc[i];
        bc[i] = (c > 0) ? atomicAdd(&gcur[i], c) : 0;
    }
    __syncthreads();
    for (int e = base + t; e < end; e += 256) {
        int s = esrc[e];
        int pos = atomicAdd(&bc[s >> BSH], 1);
        binned[pos] = ((unsigned int)(s & (BNODES - 1)) << 17) | (unsigned int)edst[e];
    }
}

// per-bucket fine sort: LDS per-node hist + scan, write offs/deg and slots
__global__ __launch_bounds__(256) void binfine_kernel(
    const unsigned int* __restrict__ binned,
    const int* __restrict__ counts, const int* __restrict__ bbase,
    const int* __restrict__ sbase,
    int* __restrict__ offs, int* __restrict__ deg,
    int* __restrict__ slots, int n_nodes)
{
    __shared__ int dcnt[BNODES];
    __shared__ int sc[BNODES];
    __shared__ int dcur[BNODES];
    const int t = threadIdx.x;
    const int b = blockIdx.x;
    const int cnt = counts[b];
    const int start = bbase[b];
    const int sb = sbase[b];
    const int node0 = b << BSH;

    if (t < BNODES) dcnt[t] = 0;
    __syncthreads();
    for (int i = t; i < cnt; i += 256)
        atomicAdd(&dcnt[binned[start + i] >> 17], 1);
    __syncthreads();
    int pd = 0;
    if (t < BNODES) { pd = (dcnt[t] + 3) & ~3; sc[t] = pd; }
    __syncthreads();
    for (int off = 1; off < BNODES; off <<= 1) {
        int v = 0;
        if (t < BNODES && t >= off) v = sc[t - off];
        __syncthreads();
        if (t < BNODES) sc[t] += v;
        __syncthreads();
    }
    if (t < BNODES) {
        int o = sb + sc[t] - pd;   // 4-aligned per-node start
        dcur[t] = o;
        int node = node0 + t;
        if (node < n_nodes) { offs[node] = o; deg[node] = dcnt[t]; }
    }
    __syncthreads();
    for (int i = t; i < cnt; i += 256) {
        unsigned int w = binned[start + i];
        int pos = atomicAdd(&dcur[w >> 17], 1);
        slots[pos] = (int)(w & 0x1ffffu);
    }
}

// ---------------------------------------------------------------------------
// Gather: 64 lanes per node, 2 cols per lane (bf16x2 h loads).
// v2: 32-bit byte-offset addressing + 2-stage software pipeline.
// (Left unchanged: R1 showed it sits on the L2-miss path ceiling ~3.1 TB/s.)
// ---------------------------------------------------------------------------
__global__ __launch_bounds__(256) void gather_kernel(
    const int* __restrict__ slots, const int* __restrict__ offsets,
    const int* __restrict__ deg,
    const unsigned int* __restrict__ hv,    // [N*64] packed bf16 pairs
    const float2* __restrict__ usrc, const float2* __restrict__ vdst,
    float* __restrict__ out, int n_nodes)
{
    const int t = threadIdx.x;
    const int node = blockIdx.x * 4 + (t >> 6);
    if (node >= n_nodes) return;
    const int l = t & 63;          // cols {2l, 2l+1}
    const int head = l >> 4;
    const unsigned loff = (unsigned)l << 2;     // byte offset within hv row (256B)
    const unsigned hoff = (unsigned)head << 3;  // byte offset within vdst row (32B)
    const char* __restrict__ hvb = (const char*)hv;
    const char* __restrict__ vdb = (const char*)vdst;
    const float2 u = usrc[(unsigned)node * 4u + head];
    const int beg = offsets[node]; // multiple of 4
    const int d = deg[node];

    float ax0 = 0.f, ay0 = 0.f, ax1 = 0.f, ay1 = 0.f;
    float ax2 = 0.f, ay2 = 0.f, ax3 = 0.f, ay3 = 0.f;

#define LDV(c) (*(const float2*)(vdb + ((((unsigned)(c)) << 5) + hoff)))
#define LDW(c) (*(const unsigned int*)(hvb + ((((unsigned)(c)) << 8) + loff)))
#define COMP(vv, ww, AX, AY) do {                                   \
        float e_ = fminf(u.x * (vv).x, u.y * (vv).y);               \
        AX = fmaf(e_, __uint_as_float((ww) << 16), AX);             \
        AY = fmaf(e_, __uint_as_float((ww) & 0xffff0000u), AY);     \
    } while (0)

    int k = 0;
    if (d >= 4) {
        // prologue: group 0 into A
        int4 cA = *(const int4*)(slots + beg);
        float2 vA0 = LDV(cA.x), vA1 = LDV(cA.y), vA2 = LDV(cA.z), vA3 = LDV(cA.w);
        unsigned wA0 = LDW(cA.x), wA1 = LDW(cA.y), wA2 = LDW(cA.z), wA3 = LDW(cA.w);

        for (; k + 12 <= d; k += 8) {
            int4 cB = *(const int4*)(slots + beg + k + 4);
            float2 vB0 = LDV(cB.x), vB1 = LDV(cB.y), vB2 = LDV(cB.z), vB3 = LDV(cB.w);
            unsigned wB0 = LDW(cB.x), wB1 = LDW(cB.y), wB2 = LDW(cB.z), wB3 = LDW(cB.w);
            COMP(vA0, wA0, ax0, ay0); COMP(vA1, wA1, ax1, ay1);
            COMP(vA2, wA2, ax2, ay2); COMP(vA3, wA3, ax3, ay3);
            int4 cN = *(const int4*)(slots + beg + k + 8);
            vA0 = LDV(cN.x); vA1 = LDV(cN.y); vA2 = LDV(cN.z); vA3 = LDV(cN.w);
            wA0 = LDW(cN.x); wA1 = LDW(cN.y); wA2 = LDW(cN.z); wA3 = LDW(cN.w);
            COMP(vB0, wB0, ax0, ay0); COMP(vB1, wB1, ax1, ay1);
            COMP(vB2, wB2, ax2, ay2); COMP(vB3, wB3, ax3, ay3);
        }
        if (k + 8 <= d) {
            int4 cB = *(const int4*)(slots + beg + k + 4);
            float2 vB0 = LDV(cB.x), vB1 = LDV(cB.y), vB2 = LDV(cB.z), vB3 = LDV(cB.w);
            unsigned wB0 = LDW(cB.x), wB1 = LDW(cB.y), wB2 = LDW(cB.z), wB3 = LDW(cB.w);
            COMP(vA0, wA0, ax0, ay0); COMP(vA1, wA1, ax1, ay1);
            COMP(vA2, wA2, ax2, ay2); COMP(vA3, wA3, ax3, ay3);
            COMP(vB0, wB0, ax0, ay0); COMP(vB1, wB1, ax1, ay1);
            COMP(vB2, wB2, ax2, ay2); COMP(vB3, wB3, ax3, ay3);
            k += 8;
        } else {
            COMP(vA0, wA0, ax0, ay0); COMP(vA1, wA1, ax1, ay1);
            COMP(vA2, wA2, ax2, ay2); COMP(vA3, wA3, ax3, ay3);
            k += 4;
        }
    }
    for (; k < d; ++k) {
        int c = slots[beg + k];
        float2 v = LDV(c);
        unsigned w = LDW(c);
        COMP(v, w, ax0, ay0);
    }
#undef LDV
#undef LDW
#undef COMP

    float rx = (ax0 + ax1) + (ax2 + ax3);
    float ry = (ay0 + ay1) + (ay2 + ay3);
    rx = rx > 0.f ? rx : __expf(rx) - 1.f;
    ry = ry > 0.f ? ry : __expf(ry) - 1.f;
    ((float2*)out)[(unsigned)node * 64u + l] = make_float2(rx, ry);
}

extern "C" void kernel_launch(void* const* d_in, const int* in_sizes, int n_in,
                              void* d_out, int out_size, void* d_ws, size_t ws_size,
                              hipStream_t stream)
{
    const float* x  = (const float*)d_in[0];
    const float* W  = (const float*)d_in[1];
    const float* a  = (const float*)d_in[2];
    const int* esrc = (const int*)d_in[3];
    const int* edst = (const int*)d_in[4];
    const int n_nodes = in_sizes[0] / DIN;
    const int n_edges = in_sizes[3];
    float* out = (float*)d_out;

    const int nb = (n_nodes + BNODES - 1) >> BSH;

    // workspace layout
    unsigned int* hq = (unsigned int*)d_ws;                 // [N*64] bf16 pairs, 25.6MB
    float2* usrc = (float2*)(hq + (size_t)n_nodes * 64);    // [N*4]
    float2* vdst = usrc + (size_t)n_nodes * NH;             // [N*4]
    int* offs   = (int*)(vdst + (size_t)n_nodes * NH);      // [N]
    int* deg    = offs + n_nodes;                           // [N]
    int* counts = deg + n_nodes;                            // [MAXB]
    int* bbase  = counts + MAXB;                            // [MAXB]
    int* gcur   = bbase + MAXB;                             // [MAXB]
    int* sbase  = gcur + MAXB;                              // [MAXB]
    unsigned int* binned = (unsigned int*)(sbase + MAXB);   // [E]
    int* slots  = (int*)(binned + n_edges);                 // [E + 512*nb + 64]

    feat_kernel<<<(n_nodes + NPBF - 1) / NPBF, 256, 0, stream>>>(
        x, W, a, hq, usrc, vdst, counts, n_nodes);

    const int binblocks = (n_edges + EPB - 1) / EPB;
    bincount_kernel<<<binblocks, 256, 0, stream>>>(esrc, counts, n_edges, nb);
    bscan_kernel<<<1, 1024, 0, stream>>>(counts, bbase, gcur, sbase, nb);
    binscatter_kernel<<<binblocks, 256, 0, stream>>>(
        esrc, edst, gcur, binned, n_edges, nb);
    binfine_kernel<<<nb, 256, 0, stream>>>(
        binned, counts, bbase, sbase, offs, deg, slots, n_nodes);

    gather_kernel<<<(n_nodes + 3) / 4, 256, 0, stream>>>(
        slots, offs, deg, hq, usrc, vdst, out, n_nodes);
}